// Round 8
// baseline (2566.849 us; speedup 1.0000x reference)
//
#include <hip/hip_runtime.h>
#include <stddef.h>

// BiLSTM-CRF, round 8 (= round 6/7 resubmitted; both prior benches were
// infrastructure failures — container acquisition / GPU capacity — the
// kernel never ran).
// Round-5 post-mortem: k_sent fixed (41 GB -> 0.3 GB). k_gxall (811 us,
// VALU 42%) re-stages W 16x/WG with 32 barriers; k_sent barrier drains the
// just-issued gx prefetch (HBM RT inside the drain).
// This round: k_gxall acc-in-registers (stage each K-phase ONCE, 128-gate
// tile, 3 barriers); k_sent prefetch hoisted to loop top.

typedef float f32x4 __attribute__((ext_vector_type(4)));

__device__ __forceinline__ float sigm(float x){ return 1.0f/(1.0f + expf(-x)); }

// ---------------------------------------------------------------------------
// fv[b*S+s][j] = feat_b[j] + sum_f features[b][f][s] * feat_W[j][f]
__global__ __launch_bounds__(256) void k_fv(const float* __restrict__ feat,
                                            const float* __restrict__ fW,
                                            const float* __restrict__ fb,
                                            float* __restrict__ fvb)
{
  int idx = blockIdx.x*256 + threadIdx.x;
  int j = idx & 127;
  int r = idx >> 7;
  int b = r >> 7, sw = r & 127;
  const float* x = feat + b*512 + sw;
  float a = fb[j];
  a = fmaf(x[0],   fW[j*4+0], a);
  a = fmaf(x[128], fW[j*4+1], a);
  a = fmaf(x[256], fW[j*4+2], a);
  a = fmaf(x[384], fW[j*4+3], a);
  fvb[idx] = a;
}

// ---------------------------------------------------------------------------
// tab[d][c][gi] = bih[orig]+bhh[orig] + dot(Wih[orig], char_emb[c])   (gi unit-major)
__global__ __launch_bounds__(256) void k_gxc(
  const float* __restrict__ char_emb,
  const float* __restrict__ Wih_f, const float* __restrict__ bih_f, const float* __restrict__ bhh_f,
  const float* __restrict__ Wih_b, const float* __restrict__ bih_b, const float* __restrict__ bhh_b,
  float* __restrict__ tab)
{
  int idx = blockIdx.x*256 + threadIdx.x;   // 2*500*256
  int gi = idx & 255;
  int c  = (idx >> 8) % 500;
  int d  = idx / (500*256);
  const float* Wih = d ? Wih_b : Wih_f;
  int orig = (gi&3)*64 + (gi>>2);
  const float* w = Wih + orig*64;
  const float* e = char_emb + c*64;
  float a = (d?bih_b:bih_f)[orig] + (d?bhh_b:bhh_f)[orig];
  #pragma unroll 8
  for (int k=0;k<64;k++) a = fmaf(w[k], e[k], a);
  tab[idx] = a;
}

// ---------------------------------------------------------------------------
// All 16 char-LSTM steps, one kernel (round-4 version — no spills, works).
__global__ __launch_bounds__(256) void k_char(
  const int* __restrict__ chars2ix,
  const float* __restrict__ Whh_f, const float* __restrict__ Whh_b,
  const float* __restrict__ tab, float* __restrict__ chh)
{
  __shared__ __align__(16) float hbuf[8][64];   // 2 KB
  __shared__ float gbuf[8][256];                // 8 KB
  int tid = threadIdx.x, bid = blockIdx.x;
  int dir = bid >> 11, chunk = bid & 2047;
  int seq0 = chunk*8;
  const float* Whh = dir ? Whh_b : Whh_f;
  int orig = (tid&3)*64 + (tid>>2);
  float4 wr[16];
  #pragma unroll
  for (int k4=0;k4<16;k4++) wr[k4] = *(const float4*)(Whh + orig*64 + k4*4);
  for (int i=tid;i<8*64;i+=256) ((float*)hbuf)[i]=0.f;
  __syncthreads();
  const float* tb = tab + (size_t)dir*500*256;
  int u = tid & 63;
  int s0 = tid >> 6;
  float c0 = 0.f, c1 = 0.f;

  for (int t=0;t<16;t++){
    int tpos = dir ? 15-t : t;
    float acc[8];
    #pragma unroll
    for (int i=0;i<8;i++)
      acc[i] = tb[(size_t)chars2ix[(seq0+i)*16 + tpos]*256 + tid];
    #pragma unroll
    for (int k4=0;k4<16;k4++){
      float4 w = wr[k4];
      #pragma unroll
      for (int i=0;i<8;i++){
        const float4 h = *(const float4*)&hbuf[i][k4*4];
        acc[i] = fmaf(h.x,w.x, fmaf(h.y,w.y, fmaf(h.z,w.z, fmaf(h.w,w.w, acc[i]))));
      }
    }
    #pragma unroll
    for (int i=0;i<8;i++) gbuf[i][tid] = acc[i];
    __syncthreads();
    float gi0=gbuf[s0  ][u*4+0], gf0=gbuf[s0  ][u*4+1], gg0=gbuf[s0  ][u*4+2], go0=gbuf[s0  ][u*4+3];
    float gi1=gbuf[s0+4][u*4+0], gf1=gbuf[s0+4][u*4+1], gg1=gbuf[s0+4][u*4+2], go1=gbuf[s0+4][u*4+3];
    c0 = sigm(gf0)*c0 + sigm(gi0)*tanhf(gg0);
    c1 = sigm(gf1)*c1 + sigm(gi1)*tanhf(gg1);
    hbuf[s0  ][u] = sigm(go0)*tanhf(c0);
    hbuf[s0+4][u] = sigm(go1)*tanhf(c1);
    __syncthreads();
  }
  #pragma unroll
  for (int i=0;i<2;i++){
    int sq = s0 + i*4;
    chh[(size_t)(dir*16384 + seq0 + sq)*64 + u] = hbuf[sq][u];
  }
}

// ---------------------------------------------------------------------------
// chvec[r][j] = b2[j] + [hf|hb] @ W2[j]
__global__ __launch_bounds__(256) void k_chvec(
  const float* __restrict__ chh,
  const float* __restrict__ W2, const float* __restrict__ b2,
  float* __restrict__ chvec)
{
  __shared__ __align__(16) float Wc[64*128];
  __shared__ __align__(16) float gout[4][8][64];
  int tid = threadIdx.x, bid = blockIdx.x;
  for (int i=tid;i<64*32;i+=256){
    int l2=i>>5, k4=i&31;
    *(float4*)&Wc[(l2*128 + k4*4) ^ ((l2&7)<<2)] = *(const float4*)(W2 + l2*128 + k4*4);
  }
  __syncthreads();
  int wave = __builtin_amdgcn_readfirstlane((int)(tid>>6));
  int l = tid & 63;
  float bb = b2[l];
  for (int it=0; it<2; ++it){
    int r0 = bid*64 + it*32 + wave*8;
    float acc[8];
    #pragma unroll
    for (int i=0;i<8;i++) acc[i]=bb;
    const float* hf[8]; const float* hb[8];
    #pragma unroll
    for (int i=0;i<8;i++){ hf[i]=chh+(size_t)(r0+i)*64; hb[i]=chh+(size_t)(16384+r0+i)*64; }
    #pragma unroll
    for (int k4=0;k4<16;k4++){
      float4 w=*(const float4*)&Wc[(l*128+k4*4)^((l&7)<<2)];
      #pragma unroll
      for (int i=0;i<8;i++){
        const float4 x=*(const float4*)(hf[i]+k4*4);
        acc[i]=fmaf(x.x,w.x,fmaf(x.y,w.y,fmaf(x.z,w.z,fmaf(x.w,w.w,acc[i]))));
      }
    }
    #pragma unroll
    for (int k4=0;k4<16;k4++){
      float4 w=*(const float4*)&Wc[(l*128+64+k4*4)^((l&7)<<2)];
      #pragma unroll
      for (int i=0;i<8;i++){
        const float4 x=*(const float4*)(hb[i]+k4*4);
        acc[i]=fmaf(x.x,w.x,fmaf(x.y,w.y,fmaf(x.z,w.z,fmaf(x.w,w.w,acc[i]))));
      }
    }
    #pragma unroll
    for (int i=0;i<8;i++) gout[wave][i][l]=acc[i];
    int rsub=l>>3, cg=l&7;
    #pragma unroll
    for (int i2=0;i2<2;i2++){
      int col=cg*8+i2*4;
      *(float4*)&chvec[(size_t)(r0+rsub)*64+col] = *(const float4*)&gout[wave][rsub][col];
    }
  }
}

// ---------------------------------------------------------------------------
// Fused input GEMM, acc-in-registers. grid 2048 = ct2(8) x dir(2) x rch(128).
// WG: 128-gate tile x 128 rows; W phase (128x160, 80 KB, XOR-swz) staged ONCE;
// acc[4 its][2 g][8 rows] lives in regs across both K-phases. 3 barriers total.
__global__ __launch_bounds__(256, 2) void k_gxall(
  const int* __restrict__ words2ix, const float* __restrict__ word_emb,
  const float* __restrict__ chvec, const float* __restrict__ fvb,
  const float* __restrict__ Wih_f, const float* __restrict__ bih_f, const float* __restrict__ bhh_f,
  const float* __restrict__ Wih_b, const float* __restrict__ bih_b, const float* __restrict__ bhh_b,
  float* __restrict__ gxf, float* __restrict__ gxb)
{
  __shared__ __align__(16) float Wg[128*160];   // 80 KB
  int tid=threadIdx.x, bid=blockIdx.x;
  int ct2 = bid & 7, dir = (bid>>3)&1, rch = bid>>4;   // rch 0..127
  const float* Wih = dir ? Wih_b : Wih_f;
  const float* bihp = dir ? bih_b : bih_f;
  const float* bhhp = dir ? bhh_b : bhh_f;
  float* gx = dir ? gxb : gxf;
  int wave = __builtin_amdgcn_readfirstlane((int)(tid>>6));
  int l = tid & 63;
  int swz = (l&7)<<2;
  float bias0, bias1;
  { int g0 = ct2*128 + l;      int o0 = (g0&3)*256 + (g0>>2); bias0 = bihp[o0]+bhhp[o0];
    int g1 = ct2*128 + 64 + l; int o1 = (g1&3)*256 + (g1>>2); bias1 = bihp[o1]+bhhp[o1]; }
  float acc[4][2][8];
  #pragma unroll
  for (int it=0; it<4; ++it)
    #pragma unroll
    for (int rr=0; rr<8; ++rr){ acc[it][0][rr]=bias0; acc[it][1][rr]=bias1; }

  // ---- phase 0: K cols 0..159  (we 0..127 | chvec 0..31)
  for (int i=tid; i<128*40; i+=256){
    int g = i/40, k4 = i%40;
    int gg = ct2*128 + g, orig = (gg&3)*256 + (gg>>2);
    *(float4*)&Wg[(g*160 + k4*4) ^ ((g&7)<<2)] = *(const float4*)(Wih + orig*320 + k4*4);
  }
  __syncthreads();
  #pragma unroll
  for (int it=0; it<4; ++it){
    const float *wp[8], *cp[8];
    #pragma unroll
    for (int rr=0; rr<8; ++rr){
      int r = rch*128 + it*32 + wave*8 + rr;
      int b=r&127, sw=r>>7; int rid=b*128+sw;
      wp[rr] = word_emb + (size_t)words2ix[rid]*128;
      cp[rr] = chvec + (size_t)rid*64;
    }
    for (int k4=0;k4<32;k4++){
      float4 w0=*(const float4*)&Wg[(l*160 + k4*4) ^ swz];
      float4 w1=*(const float4*)&Wg[((l+64)*160 + k4*4) ^ swz];
      #pragma unroll
      for (int rr=0; rr<8; ++rr){
        const float4 x=*(const float4*)(wp[rr]+k4*4);
        acc[it][0][rr]=fmaf(x.x,w0.x,fmaf(x.y,w0.y,fmaf(x.z,w0.z,fmaf(x.w,w0.w,acc[it][0][rr]))));
        acc[it][1][rr]=fmaf(x.x,w1.x,fmaf(x.y,w1.y,fmaf(x.z,w1.z,fmaf(x.w,w1.w,acc[it][1][rr]))));
      }
    }
    for (int k4=32;k4<40;k4++){
      float4 w0=*(const float4*)&Wg[(l*160 + k4*4) ^ swz];
      float4 w1=*(const float4*)&Wg[((l+64)*160 + k4*4) ^ swz];
      #pragma unroll
      for (int rr=0; rr<8; ++rr){
        const float4 x=*(const float4*)(cp[rr]+(k4-32)*4);
        acc[it][0][rr]=fmaf(x.x,w0.x,fmaf(x.y,w0.y,fmaf(x.z,w0.z,fmaf(x.w,w0.w,acc[it][0][rr]))));
        acc[it][1][rr]=fmaf(x.x,w1.x,fmaf(x.y,w1.y,fmaf(x.z,w1.z,fmaf(x.w,w1.w,acc[it][1][rr]))));
      }
    }
  }
  __syncthreads();
  // ---- phase 1: K cols 160..319  (chvec 32..63 | fv 0..127)
  for (int i=tid; i<128*40; i+=256){
    int g = i/40, k4 = i%40;
    int gg = ct2*128 + g, orig = (gg&3)*256 + (gg>>2);
    *(float4*)&Wg[(g*160 + k4*4) ^ ((g&7)<<2)] = *(const float4*)(Wih + orig*320 + 160 + k4*4);
  }
  __syncthreads();
  #pragma unroll
  for (int it=0; it<4; ++it){
    const float *cp[8], *fp[8];
    #pragma unroll
    for (int rr=0; rr<8; ++rr){
      int r = rch*128 + it*32 + wave*8 + rr;
      int b=r&127, sw=r>>7; int rid=b*128+sw;
      cp[rr] = chvec + (size_t)rid*64;
      fp[rr] = fvb + (size_t)rid*128;
    }
    for (int k4=0;k4<8;k4++){
      float4 w0=*(const float4*)&Wg[(l*160 + k4*4) ^ swz];
      float4 w1=*(const float4*)&Wg[((l+64)*160 + k4*4) ^ swz];
      #pragma unroll
      for (int rr=0; rr<8; ++rr){
        const float4 x=*(const float4*)(cp[rr]+32+k4*4);
        acc[it][0][rr]=fmaf(x.x,w0.x,fmaf(x.y,w0.y,fmaf(x.z,w0.z,fmaf(x.w,w0.w,acc[it][0][rr]))));
        acc[it][1][rr]=fmaf(x.x,w1.x,fmaf(x.y,w1.y,fmaf(x.z,w1.z,fmaf(x.w,w1.w,acc[it][1][rr]))));
      }
    }
    for (int k4=8;k4<40;k4++){
      float4 w0=*(const float4*)&Wg[(l*160 + k4*4) ^ swz];
      float4 w1=*(const float4*)&Wg[((l+64)*160 + k4*4) ^ swz];
      #pragma unroll
      for (int rr=0; rr<8; ++rr){
        const float4 x=*(const float4*)(fp[rr]+(k4-8)*4);
        acc[it][0][rr]=fmaf(x.x,w0.x,fmaf(x.y,w0.y,fmaf(x.z,w0.z,fmaf(x.w,w0.w,acc[it][0][rr]))));
        acc[it][1][rr]=fmaf(x.x,w1.x,fmaf(x.y,w1.y,fmaf(x.z,w1.z,fmaf(x.w,w1.w,acc[it][1][rr]))));
      }
    }
  }
  // ---- write (lane-contiguous 256 B dword stores)
  #pragma unroll
  for (int it=0; it<4; ++it)
    #pragma unroll
    for (int rr=0; rr<8; ++rr){
      int r = rch*128 + it*32 + wave*8 + rr;
      gx[(size_t)r*1024 + ct2*128 + l]      = acc[it][0][rr];
      gx[(size_t)r*1024 + ct2*128 + 64 + l] = acc[it][1][rr];
    }
}

// ---------------------------------------------------------------------------
// Persistent sentence BiLSTM (round-5 structure; gx prefetch hoisted to loop
// top so the barrier's vmcnt(0) drain no longer pays the HBM round trip).
__global__ __launch_bounds__(512, 2) void k_sent(
  const float* __restrict__ gxf, const float* __restrict__ gxb,
  const float* __restrict__ Whh_f, const float* __restrict__ Whh_b,
  float* __restrict__ hA, float* __restrict__ hB,
  float* __restrict__ hsf, float* __restrict__ hsb,
  unsigned int* __restrict__ cnt)
{
  __shared__ __align__(16) float Wl[128*260];
  __shared__ __align__(16) float hstage[8*264];
  __shared__ float gbuf[8*16*10];
  int tid=threadIdx.x, bid=blockIdx.x;
  int gt = bid & 7, dir = (bid>>3)&1, chunk = bid>>4;
  int grp = bid >> 3;
  unsigned int* ctr = cnt + (grp<<6);
  const float* Whh = dir ? Whh_b : Whh_f;
  const float* gx  = dir ? gxb : gxf;
  float* hs = dir ? hsb : hsf;
  int b0 = chunk*8;

  for (int i=tid; i<128*64; i+=512){
    int g = i>>6, k4 = i&63;
    int gi = gt*128 + g, orig = (gi&3)*256 + (gi>>2);
    *(float4*)&Wl[g*260 + k4*4] = *(const float4*)(Whh + orig*256 + k4*4);
  }
  for (int i=tid; i<8*264; i+=512) hstage[i] = 0.f;
  __syncthreads();

  int wave = tid>>6, l = tid&63;
  int gl = l & 15, ng = l >> 4;
  int grow = wave*16 + gl;
  int ul = l >> 3, nn = l & 7;
  int au = gt*32 + wave*4 + ul;
  float creg = 0.f;
  float nxt[2];
  {
    int spos0 = dir ? 127 : 0;
    #pragma unroll
    for (int i=0;i<2;i++)
      nxt[i] = gx[(size_t)(spos0*128 + b0 + ng*2 + i)*1024 + gt*128 + grow];
  }

  for (int t=0; t<128; ++t){
    int spos = dir ? 127 - t : t;
    float acc0 = nxt[0], acc1 = nxt[1];
    // prefetch t+1 FIRST: full FMA loop hides the HBM latency, so the
    // barrier's vmcnt(0) drain is ~free.
    if (t < 127){
      int sposn = dir ? 126 - t : t+1;
      #pragma unroll
      for (int i=0;i<2;i++)
        nxt[i] = gx[(size_t)(sposn*128 + b0 + ng*2 + i)*1024 + gt*128 + grow];
    }
    #pragma unroll 8
    for (int k4=0;k4<64;k4++){
      float4 w  = *(const float4*)&Wl[grow*260 + k4*4];
      float4 x0 = *(const float4*)&hstage[(ng*2+0)*264 + k4*4];
      float4 x1 = *(const float4*)&hstage[(ng*2+1)*264 + k4*4];
      acc0 = fmaf(x0.x,w.x, fmaf(x0.y,w.y, fmaf(x0.z,w.z, fmaf(x0.w,w.w, acc0))));
      acc1 = fmaf(x1.x,w.x, fmaf(x1.y,w.y, fmaf(x1.z,w.z, fmaf(x1.w,w.w, acc1))));
    }
    gbuf[(wave*16 + gl)*10 + ng*2+0] = acc0;
    gbuf[(wave*16 + gl)*10 + ng*2+1] = acc1;
    if (l < 32){
      float g_i = gbuf[(wave*16 + ul*4+0)*10 + nn];
      float g_f = gbuf[(wave*16 + ul*4+1)*10 + nn];
      float g_g = gbuf[(wave*16 + ul*4+2)*10 + nn];
      float g_o = gbuf[(wave*16 + ul*4+3)*10 + nn];
      creg = sigm(g_f)*creg + sigm(g_i)*tanhf(g_g);
      float h = sigm(g_o)*tanhf(creg);
      float* hn = ((t&1)==0) ? hB : hA;
      __hip_atomic_store(&hn[(size_t)(dir*128 + b0 + nn)*256 + au], h,
                         __ATOMIC_RELAXED, __HIP_MEMORY_SCOPE_AGENT);
      hs[(size_t)(spos*128 + b0 + nn)*256 + au] = h;
    }
    __syncthreads();   // drains vmcnt(0): h stores acked at coherence point
    if (tid==0){
      atomicAdd(ctr, 1u);
      unsigned int target = 8u*(unsigned)(t+1);
      while (__hip_atomic_load(ctr, __ATOMIC_RELAXED, __HIP_MEMORY_SCOPE_AGENT) < target)
        __builtin_amdgcn_s_sleep(2);
    }
    __syncthreads();
    if (t < 127){
      const float* hc = ((t&1)==0) ? hB : hA;
      int row = tid >> 6, col4 = (tid & 63) * 4;
      const float* p = &hc[(size_t)(dir*128 + b0 + row)*256 + col4];
      f32x4 v;
      asm volatile("global_load_dwordx4 %0, %1, off sc0 sc1"
                   : "=v"(v) : "v"(p) : "memory");
      asm volatile("s_waitcnt vmcnt(0)" ::: "memory");
      __builtin_amdgcn_sched_barrier(0);
      *(f32x4*)&hstage[row*264 + col4] = v;
      __syncthreads();
    }
  }
}

// ---------------------------------------------------------------------------
// feats[b*128+s][k] = tag_b[k] + [hsf|hsb|chvec|fv] . tag_W[k]  (K=704, 2 passes)
__global__ __launch_bounds__(256) void k_feats(
  const float* __restrict__ hsf, const float* __restrict__ hsb,
  const float* __restrict__ chvec, const float* __restrict__ fvb,
  const float* __restrict__ tagW, const float* __restrict__ tagb,
  float* __restrict__ feats)
{
  __shared__ __align__(16) float Wt[27*352];
  int tid=threadIdx.x, bid=blockIdx.x;
  int wave=__builtin_amdgcn_readfirstlane((int)(tid>>6));
  int l=tid&63;
  int r0=bid*32+wave*8;
  bool act = (l < 27);
  float acc[8];
  #pragma unroll
  for (int i=0;i<8;i++) acc[i] = act ? tagb[l] : 0.f;
  const float* hfr[8]; const float* hbr[8]; const float* cr[8]; const float* fr[8];
  #pragma unroll
  for (int i=0;i<8;i++){
    int r=r0+i; int b=r>>7, sw=r&127;
    hfr[i]=hsf + (size_t)(sw*128+b)*256;
    hbr[i]=hsb + (size_t)(sw*128+b)*256;
    cr[i]=chvec + (size_t)r*64;
    fr[i]=fvb + (size_t)r*128;
  }
  for (int i=tid;i<27*88;i+=256){
    int rr=i/88, k4=i%88;
    *(float4*)&Wt[(rr*352+k4*4)^((rr&7)<<2)] = *(const float4*)(tagW + rr*704 + k4*4);
  }
  __syncthreads();
  if (act){
    for (int k4=0;k4<64;k4++){
      float4 w=*(const float4*)&Wt[(l*352+k4*4)^((l&7)<<2)];
      #pragma unroll
      for (int i=0;i<8;i++){
        const float4 x=*(const float4*)(hfr[i]+k4*4);
        acc[i]=fmaf(x.x,w.x,fmaf(x.y,w.y,fmaf(x.z,w.z,fmaf(x.w,w.w,acc[i]))));
      }
    }
    for (int k4=64;k4<88;k4++){
      float4 w=*(const float4*)&Wt[(l*352+k4*4)^((l&7)<<2)];
      #pragma unroll
      for (int i=0;i<8;i++){
        const float4 x=*(const float4*)(hbr[i]+(k4-64)*4);
        acc[i]=fmaf(x.x,w.x,fmaf(x.y,w.y,fmaf(x.z,w.z,fmaf(x.w,w.w,acc[i]))));
      }
    }
  }
  __syncthreads();
  for (int i=tid;i<27*88;i+=256){
    int rr=i/88, k4=i%88;
    *(float4*)&Wt[(rr*352+k4*4)^((rr&7)<<2)] = *(const float4*)(tagW + rr*704 + 352 + k4*4);
  }
  __syncthreads();
  if (act){
    for (int k4=0;k4<40;k4++){
      float4 w=*(const float4*)&Wt[(l*352+k4*4)^((l&7)<<2)];
      #pragma unroll
      for (int i=0;i<8;i++){
        const float4 x=*(const float4*)(hbr[i]+96+k4*4);
        acc[i]=fmaf(x.x,w.x,fmaf(x.y,w.y,fmaf(x.z,w.z,fmaf(x.w,w.w,acc[i]))));
      }
    }
    for (int k4=40;k4<56;k4++){
      float4 w=*(const float4*)&Wt[(l*352+k4*4)^((l&7)<<2)];
      #pragma unroll
      for (int i=0;i<8;i++){
        const float4 x=*(const float4*)(cr[i]+(k4-40)*4);
        acc[i]=fmaf(x.x,w.x,fmaf(x.y,w.y,fmaf(x.z,w.z,fmaf(x.w,w.w,acc[i]))));
      }
    }
    for (int k4=56;k4<88;k4++){
      float4 w=*(const float4*)&Wt[(l*352+k4*4)^((l&7)<<2)];
      #pragma unroll
      for (int i=0;i<8;i++){
        const float4 x=*(const float4*)(fr[i]+(k4-56)*4);
        acc[i]=fmaf(x.x,w.x,fmaf(x.y,w.y,fmaf(x.z,w.z,fmaf(x.w,w.w,acc[i]))));
      }
    }
    #pragma unroll
    for (int i=0;i<8;i++) feats[(size_t)(r0+i)*27 + l] = acc[i];
  }
}

// ---------------------------------------------------------------------------
__global__ __launch_bounds__(256) void k_argmax(const float* __restrict__ feats,
                                                float* __restrict__ out)
{
  int r = blockIdx.x*256 + threadIdx.x;
  const float* f = feats + (size_t)r*27;
  float best = f[0]; int bi = 0;
  #pragma unroll
  for (int j=1;j<27;j++){ float v=f[j]; if (v>best){best=v;bi=j;} }
  out[r] = (float)bi;
}

// ---------------------------------------------------------------------------
__global__ __launch_bounds__(64) void k_viterbi(
  const float* __restrict__ feats, const int* __restrict__ mask,
  const float* __restrict__ trans, float* __restrict__ out)
{
  __shared__ float tr[729];
  __shared__ unsigned char bp[127][27];
  __shared__ int tags[128];
  int b = blockIdx.x, l = threadIdx.x;
  for (int i=l;i<729;i+=64) tr[i]=trans[i];
  __syncthreads();
  int ll = (l<27) ? l : 0;
  float trc[27];
  #pragma unroll
  for (int i=0;i<27;i++) trc[i]=tr[i*27+ll];
  const float* fb_ = feats + (size_t)b*128*27;
  float score = fb_[ll] + tr[25*27 + ll];
  for (int t=1;t<128;t++){
    float best=-3.0e38f; int bi=0;
    #pragma unroll 1
    for (int i=0;i<27;i++){
      float si = __shfl(score, i, 64);
      float cand = si + trc[i];
      if (cand > best){ best=cand; bi=i; }
    }
    int m = mask[b*128 + t];
    float ns = best + fb_[t*27 + ll];
    if (m) score = ns;
    int bpv = m ? bi : ll;
    if (l < 27) bp[t-1][l] = (unsigned char)bpv;
  }
  float fin = score + tr[ll*27 + 26];
  if (l >= 27) fin = -3.0e38f;
  float bestf=-3.0e38f; int bt=0;
  #pragma unroll 1
  for (int i=0;i<27;i++){
    float v=__shfl(fin, i, 64);
    if (v > bestf){ bestf=v; bt=i; }
  }
  if (l==0){
    out[b]=bestf;
    int tg=bt; tags[127]=tg;
    for (int t=126;t>=0;t--){ tg = bp[t][tg]; tags[t]=tg; }
  }
  __syncthreads();
  float* op = out + 128 + b*128;
  for (int t=l;t<128;t+=64) op[t]=(float)tags[t];
}

// ---------------------------------------------------------------------------
extern "C" void kernel_launch(void* const* d_in, const int* in_sizes, int n_in,
                              void* d_out, int out_size, void* d_ws, size_t ws_size,
                              hipStream_t stream)
{
  (void)in_sizes; (void)n_in; (void)out_size; (void)ws_size;
  const int*   words2ix = (const int*)d_in[0];
  const int*   chars2ix = (const int*)d_in[1];
  const float* features = (const float*)d_in[2];
  const int*   amask    = (const int*)d_in[3];
  const float* word_emb = (const float*)d_in[4];
  const float* char_emb = (const float*)d_in[5];
  const float* cWih_f=(const float*)d_in[6],  *cWhh_f=(const float*)d_in[7];
  const float* cbih_f=(const float*)d_in[8],  *cbhh_f=(const float*)d_in[9];
  const float* cWih_b=(const float*)d_in[10], *cWhh_b=(const float*)d_in[11];
  const float* cbih_b=(const float*)d_in[12], *cbhh_b=(const float*)d_in[13];
  const float* coW=(const float*)d_in[14], *cob=(const float*)d_in[15];
  const float* fW =(const float*)d_in[16], *fb =(const float*)d_in[17];
  const float* lWih_f=(const float*)d_in[18], *lWhh_f=(const float*)d_in[19];
  const float* lbih_f=(const float*)d_in[20], *lbhh_f=(const float*)d_in[21];
  const float* lWih_b=(const float*)d_in[22], *lWhh_b=(const float*)d_in[23];
  const float* lbih_b=(const float*)d_in[24], *lbhh_b=(const float*)d_in[25];
  const float* tagW=(const float*)d_in[26], *tagb=(const float*)d_in[27];
  const float* trans=(const float*)d_in[28];
  float* out = (float*)d_out;

  float* p = (float*)d_ws;
  float* chvec = p; p += 16384*64;
  float* fvb   = p; p += 16384*128;
  float* gxf   = p; p += (size_t)16384*1024;
  float* gxb   = p; p += (size_t)16384*1024;
  float* chh   = p; p += 2*16384*64;
  float* tab   = p; p += 2*500*256;
  float* hA    = p; p += 2*128*256;
  float* hB    = p; p += 2*128*256;
  float* hsf   = p; p += (size_t)128*128*256;
  float* hsb   = p; p += (size_t)128*128*256;
  float* feats = p; p += 16384*27;
  unsigned int* cnt = (unsigned int*)p;   // 32 groups x 64 uints (padded)

  hipMemsetAsync(cnt, 0, 32*64*sizeof(unsigned int), stream);

  k_gxc<<<1000,256,0,stream>>>(char_emb, cWih_f,cbih_f,cbhh_f, cWih_b,cbih_b,cbhh_b, tab);
  k_fv<<<8192,256,0,stream>>>(features, fW, fb, fvb);
  k_char<<<4096,256,0,stream>>>(chars2ix, cWhh_f, cWhh_b, tab, chh);
  k_chvec<<<256,256,0,stream>>>(chh, coW, cob, chvec);
  k_gxall<<<2048,256,0,stream>>>(words2ix, word_emb, chvec, fvb,
      lWih_f,lbih_f,lbhh_f, lWih_b,lbih_b,lbhh_b, gxf, gxb);
  k_sent<<<256,512,0,stream>>>(gxf, gxb, lWhh_f, lWhh_b, hA, hB, hsf, hsb, cnt);
  k_feats<<<512,256,0,stream>>>(hsf, hsb, chvec, fvb, tagW, tagb, feats);
  k_argmax<<<64,256,0,stream>>>(feats, out + 128 + 16384);
  k_viterbi<<<128,64,0,stream>>>(feats, amask, trans, out);
}

// Round 9
// 2485.356 us; speedup vs baseline: 1.0328x; 1.0328x over previous
//
#include <hip/hip_runtime.h>
#include <stddef.h>

// BiLSTM-CRF, round 9.
// Round-8 post-mortem: k_gxall acc[4][2][8]=64 regs hit the (256,2) 128-VGPR
// cap -> spills (FETCH+70MB/WRITE+129MB = scratch traffic), 811->1075 us.
// Also the XOR swizzle never fixed b128 reads (8-way inherent; 2.1e7 conflicts).
// This round: k_gxall v3 — acc[4][8]=32 regs (64 gates x 128 rows/WG),
// TRANSPOSED W in LDS (conflict-free b32 reads, cheap addressing),
// 40 KB LDS -> 4 WGs/CU, launch_bounds(256,4). Everything else unchanged.

typedef float f32x4 __attribute__((ext_vector_type(4)));

__device__ __forceinline__ float sigm(float x){ return 1.0f/(1.0f + expf(-x)); }

// ---------------------------------------------------------------------------
// fv[b*S+s][j] = feat_b[j] + sum_f features[b][f][s] * feat_W[j][f]
__global__ __launch_bounds__(256) void k_fv(const float* __restrict__ feat,
                                            const float* __restrict__ fW,
                                            const float* __restrict__ fb,
                                            float* __restrict__ fvb)
{
  int idx = blockIdx.x*256 + threadIdx.x;
  int j = idx & 127;
  int r = idx >> 7;
  int b = r >> 7, sw = r & 127;
  const float* x = feat + b*512 + sw;
  float a = fb[j];
  a = fmaf(x[0],   fW[j*4+0], a);
  a = fmaf(x[128], fW[j*4+1], a);
  a = fmaf(x[256], fW[j*4+2], a);
  a = fmaf(x[384], fW[j*4+3], a);
  fvb[idx] = a;
}

// ---------------------------------------------------------------------------
// tab[d][c][gi] = bih[orig]+bhh[orig] + dot(Wih[orig], char_emb[c])   (gi unit-major)
__global__ __launch_bounds__(256) void k_gxc(
  const float* __restrict__ char_emb,
  const float* __restrict__ Wih_f, const float* __restrict__ bih_f, const float* __restrict__ bhh_f,
  const float* __restrict__ Wih_b, const float* __restrict__ bih_b, const float* __restrict__ bhh_b,
  float* __restrict__ tab)
{
  int idx = blockIdx.x*256 + threadIdx.x;   // 2*500*256
  int gi = idx & 255;
  int c  = (idx >> 8) % 500;
  int d  = idx / (500*256);
  const float* Wih = d ? Wih_b : Wih_f;
  int orig = (gi&3)*64 + (gi>>2);
  const float* w = Wih + orig*64;
  const float* e = char_emb + c*64;
  float a = (d?bih_b:bih_f)[orig] + (d?bhh_b:bhh_f)[orig];
  #pragma unroll 8
  for (int k=0;k<64;k++) a = fmaf(w[k], e[k], a);
  tab[idx] = a;
}

// ---------------------------------------------------------------------------
// All 16 char-LSTM steps, one kernel (round-4 version — no spills, works).
__global__ __launch_bounds__(256) void k_char(
  const int* __restrict__ chars2ix,
  const float* __restrict__ Whh_f, const float* __restrict__ Whh_b,
  const float* __restrict__ tab, float* __restrict__ chh)
{
  __shared__ __align__(16) float hbuf[8][64];   // 2 KB
  __shared__ float gbuf[8][256];                // 8 KB
  int tid = threadIdx.x, bid = blockIdx.x;
  int dir = bid >> 11, chunk = bid & 2047;
  int seq0 = chunk*8;
  const float* Whh = dir ? Whh_b : Whh_f;
  int orig = (tid&3)*64 + (tid>>2);
  float4 wr[16];
  #pragma unroll
  for (int k4=0;k4<16;k4++) wr[k4] = *(const float4*)(Whh + orig*64 + k4*4);
  for (int i=tid;i<8*64;i+=256) ((float*)hbuf)[i]=0.f;
  __syncthreads();
  const float* tb = tab + (size_t)dir*500*256;
  int u = tid & 63;
  int s0 = tid >> 6;
  float c0 = 0.f, c1 = 0.f;

  for (int t=0;t<16;t++){
    int tpos = dir ? 15-t : t;
    float acc[8];
    #pragma unroll
    for (int i=0;i<8;i++)
      acc[i] = tb[(size_t)chars2ix[(seq0+i)*16 + tpos]*256 + tid];
    #pragma unroll
    for (int k4=0;k4<16;k4++){
      float4 w = wr[k4];
      #pragma unroll
      for (int i=0;i<8;i++){
        const float4 h = *(const float4*)&hbuf[i][k4*4];
        acc[i] = fmaf(h.x,w.x, fmaf(h.y,w.y, fmaf(h.z,w.z, fmaf(h.w,w.w, acc[i]))));
      }
    }
    #pragma unroll
    for (int i=0;i<8;i++) gbuf[i][tid] = acc[i];
    __syncthreads();
    float gi0=gbuf[s0  ][u*4+0], gf0=gbuf[s0  ][u*4+1], gg0=gbuf[s0  ][u*4+2], go0=gbuf[s0  ][u*4+3];
    float gi1=gbuf[s0+4][u*4+0], gf1=gbuf[s0+4][u*4+1], gg1=gbuf[s0+4][u*4+2], go1=gbuf[s0+4][u*4+3];
    c0 = sigm(gf0)*c0 + sigm(gi0)*tanhf(gg0);
    c1 = sigm(gf1)*c1 + sigm(gi1)*tanhf(gg1);
    hbuf[s0  ][u] = sigm(go0)*tanhf(c0);
    hbuf[s0+4][u] = sigm(go1)*tanhf(c1);
    __syncthreads();
  }
  #pragma unroll
  for (int i=0;i<2;i++){
    int sq = s0 + i*4;
    chh[(size_t)(dir*16384 + seq0 + sq)*64 + u] = hbuf[sq][u];
  }
}

// ---------------------------------------------------------------------------
// chvec[r][j] = b2[j] + [hf|hb] @ W2[j]
__global__ __launch_bounds__(256) void k_chvec(
  const float* __restrict__ chh,
  const float* __restrict__ W2, const float* __restrict__ b2,
  float* __restrict__ chvec)
{
  __shared__ __align__(16) float Wc[64*128];
  __shared__ __align__(16) float gout[4][8][64];
  int tid = threadIdx.x, bid = blockIdx.x;
  for (int i=tid;i<64*32;i+=256){
    int l2=i>>5, k4=i&31;
    *(float4*)&Wc[(l2*128 + k4*4) ^ ((l2&7)<<2)] = *(const float4*)(W2 + l2*128 + k4*4);
  }
  __syncthreads();
  int wave = __builtin_amdgcn_readfirstlane((int)(tid>>6));
  int l = tid & 63;
  float bb = b2[l];
  for (int it=0; it<2; ++it){
    int r0 = bid*64 + it*32 + wave*8;
    float acc[8];
    #pragma unroll
    for (int i=0;i<8;i++) acc[i]=bb;
    const float* hf[8]; const float* hb[8];
    #pragma unroll
    for (int i=0;i<8;i++){ hf[i]=chh+(size_t)(r0+i)*64; hb[i]=chh+(size_t)(16384+r0+i)*64; }
    #pragma unroll
    for (int k4=0;k4<16;k4++){
      float4 w=*(const float4*)&Wc[(l*128+k4*4)^((l&7)<<2)];
      #pragma unroll
      for (int i=0;i<8;i++){
        const float4 x=*(const float4*)(hf[i]+k4*4);
        acc[i]=fmaf(x.x,w.x,fmaf(x.y,w.y,fmaf(x.z,w.z,fmaf(x.w,w.w,acc[i]))));
      }
    }
    #pragma unroll
    for (int k4=0;k4<16;k4++){
      float4 w=*(const float4*)&Wc[(l*128+64+k4*4)^((l&7)<<2)];
      #pragma unroll
      for (int i=0;i<8;i++){
        const float4 x=*(const float4*)(hb[i]+k4*4);
        acc[i]=fmaf(x.x,w.x,fmaf(x.y,w.y,fmaf(x.z,w.z,fmaf(x.w,w.w,acc[i]))));
      }
    }
    #pragma unroll
    for (int i=0;i<8;i++) gout[wave][i][l]=acc[i];
    int rsub=l>>3, cg=l&7;
    #pragma unroll
    for (int i2=0;i2<2;i2++){
      int col=cg*8+i2*4;
      *(float4*)&chvec[(size_t)(r0+rsub)*64+col] = *(const float4*)&gout[wave][rsub][col];
    }
  }
}

// ---------------------------------------------------------------------------
// Fused input GEMM v3. grid 4096 = ct(16) x dir(2) x rch(128).
// WG: 64-gate tile x 128 rows (= sentence pos rch, all 128 batch rows).
// W staged TRANSPOSED in LDS (Wt[k][gate], conflict-free b32 reads, cheap
// base+k*256B addressing); each K-phase staged ONCE; acc[4][8]=32 regs.
__global__ __launch_bounds__(256, 4) void k_gxall(
  const int* __restrict__ words2ix, const float* __restrict__ word_emb,
  const float* __restrict__ chvec, const float* __restrict__ fvb,
  const float* __restrict__ Wih_f, const float* __restrict__ bih_f, const float* __restrict__ bhh_f,
  const float* __restrict__ Wih_b, const float* __restrict__ bih_b, const float* __restrict__ bhh_b,
  float* __restrict__ gxf, float* __restrict__ gxb)
{
  __shared__ float Wt[160*64];   // 40 KB, [kk][gate]
  int tid=threadIdx.x, bid=blockIdx.x;
  int ct = bid & 15, dir = (bid>>4)&1, rch = bid>>5;   // rch 0..127 = sentence pos
  const float* Wih = dir ? Wih_b : Wih_f;
  const float* bihp = dir ? bih_b : bih_f;
  const float* bhhp = dir ? bhh_b : bhh_f;
  float* gx = dir ? gxb : gxf;
  int wave = __builtin_amdgcn_readfirstlane((int)(tid>>6));
  int l = tid & 63;
  float acc[4][8];
  {
    int gg = ct*64 + l, og = (gg&3)*256 + (gg>>2);
    float bias = bihp[og] + bhhp[og];
    #pragma unroll
    for (int it=0; it<4; ++it)
      #pragma unroll
      for (int rr=0; rr<8; ++rr) acc[it][rr] = bias;
  }

  // ---- phase 0: K cols 0..159  (word_emb 0..127 | chvec 0..31)
  for (int i=tid; i<64*40; i+=256){
    int g = i & 63, q = i >> 6;
    int gg = ct*64 + g, orig = (gg&3)*256 + (gg>>2);
    float4 v = *(const float4*)(Wih + orig*320 + q*4);
    Wt[(q*4+0)*64 + g] = v.x;
    Wt[(q*4+1)*64 + g] = v.y;
    Wt[(q*4+2)*64 + g] = v.z;
    Wt[(q*4+3)*64 + g] = v.w;
  }
  __syncthreads();
  #pragma unroll
  for (int it=0; it<4; ++it){
    int ob = it*32 + wave*8;
    const float* xr[8];
    #pragma unroll
    for (int rr=0; rr<8; ++rr)
      xr[rr] = word_emb + (size_t)words2ix[(ob+rr)*128 + rch]*128;
    #pragma unroll 4
    for (int q=0; q<32; ++q){
      float w0=Wt[(q*4+0)*64+l], w1=Wt[(q*4+1)*64+l];
      float w2=Wt[(q*4+2)*64+l], w3=Wt[(q*4+3)*64+l];
      #pragma unroll
      for (int rr=0; rr<8; ++rr){
        const float4 x = *(const float4*)(xr[rr] + q*4);
        acc[it][rr] = fmaf(x.x,w0, fmaf(x.y,w1, fmaf(x.z,w2, fmaf(x.w,w3, acc[it][rr]))));
      }
    }
    #pragma unroll
    for (int rr=0; rr<8; ++rr)
      xr[rr] = chvec + (size_t)((ob+rr)*128 + rch)*64;
    #pragma unroll
    for (int q=32; q<40; ++q){
      float w0=Wt[(q*4+0)*64+l], w1=Wt[(q*4+1)*64+l];
      float w2=Wt[(q*4+2)*64+l], w3=Wt[(q*4+3)*64+l];
      #pragma unroll
      for (int rr=0; rr<8; ++rr){
        const float4 x = *(const float4*)(xr[rr] + (q-32)*4);
        acc[it][rr] = fmaf(x.x,w0, fmaf(x.y,w1, fmaf(x.z,w2, fmaf(x.w,w3, acc[it][rr]))));
      }
    }
  }
  __syncthreads();
  // ---- phase 1: K cols 160..319  (chvec 32..63 | fv 0..127)
  for (int i=tid; i<64*40; i+=256){
    int g = i & 63, q = i >> 6;
    int gg = ct*64 + g, orig = (gg&3)*256 + (gg>>2);
    float4 v = *(const float4*)(Wih + orig*320 + 160 + q*4);
    Wt[(q*4+0)*64 + g] = v.x;
    Wt[(q*4+1)*64 + g] = v.y;
    Wt[(q*4+2)*64 + g] = v.z;
    Wt[(q*4+3)*64 + g] = v.w;
  }
  __syncthreads();
  #pragma unroll
  for (int it=0; it<4; ++it){
    int ob = it*32 + wave*8;
    const float* xr[8];
    #pragma unroll
    for (int rr=0; rr<8; ++rr)
      xr[rr] = chvec + (size_t)((ob+rr)*128 + rch)*64;
    #pragma unroll
    for (int q=0; q<8; ++q){
      float w0=Wt[(q*4+0)*64+l], w1=Wt[(q*4+1)*64+l];
      float w2=Wt[(q*4+2)*64+l], w3=Wt[(q*4+3)*64+l];
      #pragma unroll
      for (int rr=0; rr<8; ++rr){
        const float4 x = *(const float4*)(xr[rr] + 32 + q*4);
        acc[it][rr] = fmaf(x.x,w0, fmaf(x.y,w1, fmaf(x.z,w2, fmaf(x.w,w3, acc[it][rr]))));
      }
    }
    #pragma unroll
    for (int rr=0; rr<8; ++rr)
      xr[rr] = fvb + (size_t)((ob+rr)*128 + rch)*128;
    #pragma unroll 4
    for (int q=8; q<40; ++q){
      float w0=Wt[(q*4+0)*64+l], w1=Wt[(q*4+1)*64+l];
      float w2=Wt[(q*4+2)*64+l], w3=Wt[(q*4+3)*64+l];
      #pragma unroll
      for (int rr=0; rr<8; ++rr){
        const float4 x = *(const float4*)(xr[rr] + (q-8)*4);
        acc[it][rr] = fmaf(x.x,w0, fmaf(x.y,w1, fmaf(x.z,w2, fmaf(x.w,w3, acc[it][rr]))));
      }
    }
  }
  // ---- write: wave-contiguous 256 B dword stores
  #pragma unroll
  for (int it=0; it<4; ++it)
    #pragma unroll
    for (int rr=0; rr<8; ++rr){
      int r = rch*128 + it*32 + wave*8 + rr;
      gx[(size_t)r*1024 + ct*64 + l] = acc[it][rr];
    }
}

// ---------------------------------------------------------------------------
// Persistent sentence BiLSTM (round-8 version, passed).
__global__ __launch_bounds__(512, 2) void k_sent(
  const float* __restrict__ gxf, const float* __restrict__ gxb,
  const float* __restrict__ Whh_f, const float* __restrict__ Whh_b,
  float* __restrict__ hA, float* __restrict__ hB,
  float* __restrict__ hsf, float* __restrict__ hsb,
  unsigned int* __restrict__ cnt)
{
  __shared__ __align__(16) float Wl[128*260];
  __shared__ __align__(16) float hstage[8*264];
  __shared__ float gbuf[8*16*10];
  int tid=threadIdx.x, bid=blockIdx.x;
  int gt = bid & 7, dir = (bid>>3)&1, chunk = bid>>4;
  int grp = bid >> 3;
  unsigned int* ctr = cnt + (grp<<6);
  const float* Whh = dir ? Whh_b : Whh_f;
  const float* gx  = dir ? gxb : gxf;
  float* hs = dir ? hsb : hsf;
  int b0 = chunk*8;

  for (int i=tid; i<128*64; i+=512){
    int g = i>>6, k4 = i&63;
    int gi = gt*128 + g, orig = (gi&3)*256 + (gi>>2);
    *(float4*)&Wl[g*260 + k4*4] = *(const float4*)(Whh + orig*256 + k4*4);
  }
  for (int i=tid; i<8*264; i+=512) hstage[i] = 0.f;
  __syncthreads();

  int wave = tid>>6, l = tid&63;
  int gl = l & 15, ng = l >> 4;
  int grow = wave*16 + gl;
  int ul = l >> 3, nn = l & 7;
  int au = gt*32 + wave*4 + ul;
  float creg = 0.f;
  float nxt[2];
  {
    int spos0 = dir ? 127 : 0;
    #pragma unroll
    for (int i=0;i<2;i++)
      nxt[i] = gx[(size_t)(spos0*128 + b0 + ng*2 + i)*1024 + gt*128 + grow];
  }

  for (int t=0; t<128; ++t){
    int spos = dir ? 127 - t : t;
    float acc0 = nxt[0], acc1 = nxt[1];
    if (t < 127){
      int sposn = dir ? 126 - t : t+1;
      #pragma unroll
      for (int i=0;i<2;i++)
        nxt[i] = gx[(size_t)(sposn*128 + b0 + ng*2 + i)*1024 + gt*128 + grow];
    }
    #pragma unroll 8
    for (int k4=0;k4<64;k4++){
      float4 w  = *(const float4*)&Wl[grow*260 + k4*4];
      float4 x0 = *(const float4*)&hstage[(ng*2+0)*264 + k4*4];
      float4 x1 = *(const float4*)&hstage[(ng*2+1)*264 + k4*4];
      acc0 = fmaf(x0.x,w.x, fmaf(x0.y,w.y, fmaf(x0.z,w.z, fmaf(x0.w,w.w, acc0))));
      acc1 = fmaf(x1.x,w.x, fmaf(x1.y,w.y, fmaf(x1.z,w.z, fmaf(x1.w,w.w, acc1))));
    }
    gbuf[(wave*16 + gl)*10 + ng*2+0] = acc0;
    gbuf[(wave*16 + gl)*10 + ng*2+1] = acc1;
    if (l < 32){
      float g_i = gbuf[(wave*16 + ul*4+0)*10 + nn];
      float g_f = gbuf[(wave*16 + ul*4+1)*10 + nn];
      float g_g = gbuf[(wave*16 + ul*4+2)*10 + nn];
      float g_o = gbuf[(wave*16 + ul*4+3)*10 + nn];
      creg = sigm(g_f)*creg + sigm(g_i)*tanhf(g_g);
      float h = sigm(g_o)*tanhf(creg);
      float* hn = ((t&1)==0) ? hB : hA;
      __hip_atomic_store(&hn[(size_t)(dir*128 + b0 + nn)*256 + au], h,
                         __ATOMIC_RELAXED, __HIP_MEMORY_SCOPE_AGENT);
      hs[(size_t)(spos*128 + b0 + nn)*256 + au] = h;
    }
    __syncthreads();   // drains vmcnt(0): h stores acked at coherence point
    if (tid==0){
      atomicAdd(ctr, 1u);
      unsigned int target = 8u*(unsigned)(t+1);
      while (__hip_atomic_load(ctr, __ATOMIC_RELAXED, __HIP_MEMORY_SCOPE_AGENT) < target)
        __builtin_amdgcn_s_sleep(2);
    }
    __syncthreads();
    if (t < 127){
      const float* hc = ((t&1)==0) ? hB : hA;
      int row = tid >> 6, col4 = (tid & 63) * 4;
      const float* p = &hc[(size_t)(dir*128 + b0 + row)*256 + col4];
      f32x4 v;
      asm volatile("global_load_dwordx4 %0, %1, off sc0 sc1"
                   : "=v"(v) : "v"(p) : "memory");
      asm volatile("s_waitcnt vmcnt(0)" ::: "memory");
      __builtin_amdgcn_sched_barrier(0);
      *(f32x4*)&hstage[row*264 + col4] = v;
      __syncthreads();
    }
  }
}

// ---------------------------------------------------------------------------
// feats[b*128+s][k] = tag_b[k] + [hsf|hsb|chvec|fv] . tag_W[k]  (K=704, 2 passes)
__global__ __launch_bounds__(256) void k_feats(
  const float* __restrict__ hsf, const float* __restrict__ hsb,
  const float* __restrict__ chvec, const float* __restrict__ fvb,
  const float* __restrict__ tagW, const float* __restrict__ tagb,
  float* __restrict__ feats)
{
  __shared__ __align__(16) float Wt[27*352];
  int tid=threadIdx.x, bid=blockIdx.x;
  int wave=__builtin_amdgcn_readfirstlane((int)(tid>>6));
  int l=tid&63;
  int r0=bid*32+wave*8;
  bool act = (l < 27);
  float acc[8];
  #pragma unroll
  for (int i=0;i<8;i++) acc[i] = act ? tagb[l] : 0.f;
  const float* hfr[8]; const float* hbr[8]; const float* cr[8]; const float* fr[8];
  #pragma unroll
  for (int i=0;i<8;i++){
    int r=r0+i; int b=r>>7, sw=r&127;
    hfr[i]=hsf + (size_t)(sw*128+b)*256;
    hbr[i]=hsb + (size_t)(sw*128+b)*256;
    cr[i]=chvec + (size_t)r*64;
    fr[i]=fvb + (size_t)r*128;
  }
  for (int i=tid;i<27*88;i+=256){
    int rr=i/88, k4=i%88;
    *(float4*)&Wt[(rr*352+k4*4)^((rr&7)<<2)] = *(const float4*)(tagW + rr*704 + k4*4);
  }
  __syncthreads();
  if (act){
    for (int k4=0;k4<64;k4++){
      float4 w=*(const float4*)&Wt[(l*352+k4*4)^((l&7)<<2)];
      #pragma unroll
      for (int i=0;i<8;i++){
        const float4 x=*(const float4*)(hfr[i]+k4*4);
        acc[i]=fmaf(x.x,w.x,fmaf(x.y,w.y,fmaf(x.z,w.z,fmaf(x.w,w.w,acc[i]))));
      }
    }
    for (int k4=64;k4<88;k4++){
      float4 w=*(const float4*)&Wt[(l*352+k4*4)^((l&7)<<2)];
      #pragma unroll
      for (int i=0;i<8;i++){
        const float4 x=*(const float4*)(hbr[i]+(k4-64)*4);
        acc[i]=fmaf(x.x,w.x,fmaf(x.y,w.y,fmaf(x.z,w.z,fmaf(x.w,w.w,acc[i]))));
      }
    }
  }
  __syncthreads();
  for (int i=tid;i<27*88;i+=256){
    int rr=i/88, k4=i%88;
    *(float4*)&Wt[(rr*352+k4*4)^((rr&7)<<2)] = *(const float4*)(tagW + rr*704 + 352 + k4*4);
  }
  __syncthreads();
  if (act){
    for (int k4=0;k4<40;k4++){
      float4 w=*(const float4*)&Wt[(l*352+k4*4)^((l&7)<<2)];
      #pragma unroll
      for (int i=0;i<8;i++){
        const float4 x=*(const float4*)(hbr[i]+96+k4*4);
        acc[i]=fmaf(x.x,w.x,fmaf(x.y,w.y,fmaf(x.z,w.z,fmaf(x.w,w.w,acc[i]))));
      }
    }
    for (int k4=40;k4<56;k4++){
      float4 w=*(const float4*)&Wt[(l*352+k4*4)^((l&7)<<2)];
      #pragma unroll
      for (int i=0;i<8;i++){
        const float4 x=*(const float4*)(cr[i]+(k4-40)*4);
        acc[i]=fmaf(x.x,w.x,fmaf(x.y,w.y,fmaf(x.z,w.z,fmaf(x.w,w.w,acc[i]))));
      }
    }
    for (int k4=56;k4<88;k4++){
      float4 w=*(const float4*)&Wt[(l*352+k4*4)^((l&7)<<2)];
      #pragma unroll
      for (int i=0;i<8;i++){
        const float4 x=*(const float4*)(fr[i]+(k4-56)*4);
        acc[i]=fmaf(x.x,w.x,fmaf(x.y,w.y,fmaf(x.z,w.z,fmaf(x.w,w.w,acc[i]))));
      }
    }
    #pragma unroll
    for (int i=0;i<8;i++) feats[(size_t)(r0+i)*27 + l] = acc[i];
  }
}

// ---------------------------------------------------------------------------
__global__ __launch_bounds__(256) void k_argmax(const float* __restrict__ feats,
                                                float* __restrict__ out)
{
  int r = blockIdx.x*256 + threadIdx.x;
  const float* f = feats + (size_t)r*27;
  float best = f[0]; int bi = 0;
  #pragma unroll
  for (int j=1;j<27;j++){ float v=f[j]; if (v>best){best=v;bi=j;} }
  out[r] = (float)bi;
}

// ---------------------------------------------------------------------------
__global__ __launch_bounds__(64) void k_viterbi(
  const float* __restrict__ feats, const int* __restrict__ mask,
  const float* __restrict__ trans, float* __restrict__ out)
{
  __shared__ float tr[729];
  __shared__ unsigned char bp[127][27];
  __shared__ int tags[128];
  int b = blockIdx.x, l = threadIdx.x;
  for (int i=l;i<729;i+=64) tr[i]=trans[i];
  __syncthreads();
  int ll = (l<27) ? l : 0;
  float trc[27];
  #pragma unroll
  for (int i=0;i<27;i++) trc[i]=tr[i*27+ll];
  const float* fb_ = feats + (size_t)b*128*27;
  float score = fb_[ll] + tr[25*27 + ll];
  for (int t=1;t<128;t++){
    float best=-3.0e38f; int bi=0;
    #pragma unroll 1
    for (int i=0;i<27;i++){
      float si = __shfl(score, i, 64);
      float cand = si + trc[i];
      if (cand > best){ best=cand; bi=i; }
    }
    int m = mask[b*128 + t];
    float ns = best + fb_[t*27 + ll];
    if (m) score = ns;
    int bpv = m ? bi : ll;
    if (l < 27) bp[t-1][l] = (unsigned char)bpv;
  }
  float fin = score + tr[ll*27 + 26];
  if (l >= 27) fin = -3.0e38f;
  float bestf=-3.0e38f; int bt=0;
  #pragma unroll 1
  for (int i=0;i<27;i++){
    float v=__shfl(fin, i, 64);
    if (v > bestf){ bestf=v; bt=i; }
  }
  if (l==0){
    out[b]=bestf;
    int tg=bt; tags[127]=tg;
    for (int t=126;t>=0;t--){ tg = bp[t][tg]; tags[t]=tg; }
  }
  __syncthreads();
  float* op = out + 128 + b*128;
  for (int t=l;t<128;t+=64) op[t]=(float)tags[t];
}

// ---------------------------------------------------------------------------
extern "C" void kernel_launch(void* const* d_in, const int* in_sizes, int n_in,
                              void* d_out, int out_size, void* d_ws, size_t ws_size,
                              hipStream_t stream)
{
  (void)in_sizes; (void)n_in; (void)out_size; (void)ws_size;
  const int*   words2ix = (const int*)d_in[0];
  const int*   chars2ix = (const int*)d_in[1];
  const float* features = (const float*)d_in[2];
  const int*   amask    = (const int*)d_in[3];
  const float* word_emb = (const float*)d_in[4];
  const float* char_emb = (const float*)d_in[5];
  const float* cWih_f=(const float*)d_in[6],  *cWhh_f=(const float*)d_in[7];
  const float* cbih_f=(const float*)d_in[8],  *cbhh_f=(const float*)d_in[9];
  const float* cWih_b=(const float*)d_in[10], *cWhh_b=(const float*)d_in[11];
  const float* cbih_b=(const float*)d_in[12], *cbhh_b=(const float*)d_in[13];
  const float* coW=(const float*)d_in[14], *cob=(const float*)d_in[15];
  const float* fW =(const float*)d_in[16], *fb =(const float*)d_in[17];
  const float* lWih_f=(const float*)d_in[18], *lWhh_f=(const float*)d_in[19];
  const float* lbih_f=(const float*)d_in[20], *lbhh_f=(const float*)d_in[21];
  const float* lWih_b=(const float*)d_in[22], *lWhh_b=(const float*)d_in[23];
  const float* lbih_b=(const float*)d_in[24], *lbhh_b=(const float*)d_in[25];
  const float* tagW=(const float*)d_in[26], *tagb=(const float*)d_in[27];
  const float* trans=(const float*)d_in[28];
  float* out = (float*)d_out;

  float* p = (float*)d_ws;
  float* chvec = p; p += 16384*64;
  float* fvb   = p; p += 16384*128;
  float* gxf   = p; p += (size_t)16384*1024;
  float* gxb   = p; p += (size_t)16384*1024;
  float* chh   = p; p += 2*16384*64;
  float* tab   = p; p += 2*500*256;
  float* hA    = p; p += 2*128*256;
  float* hB    = p; p += 2*128*256;
  float* hsf   = p; p += (size_t)128*128*256;
  float* hsb   = p; p += (size_t)128*128*256;
  float* feats = p; p += 16384*27;
  unsigned int* cnt = (unsigned int*)p;   // 32 groups x 64 uints (padded)

  hipMemsetAsync(cnt, 0, 32*64*sizeof(unsigned int), stream);

  k_gxc<<<1000,256,0,stream>>>(char_emb, cWih_f,cbih_f,cbhh_f, cWih_b,cbih_b,cbhh_b, tab);
  k_fv<<<8192,256,0,stream>>>(features, fW, fb, fvb);
  k_char<<<4096,256,0,stream>>>(chars2ix, cWhh_f, cWhh_b, tab, chh);
  k_chvec<<<256,256,0,stream>>>(chh, coW, cob, chvec);
  k_gxall<<<4096,256,0,stream>>>(words2ix, word_emb, chvec, fvb,
      lWih_f,lbih_f,lbhh_f, lWih_b,lbih_b,lbhh_b, gxf, gxb);
  k_sent<<<256,512,0,stream>>>(gxf, gxb, lWhh_f, lWhh_b, hA, hB, hsf, hsb, cnt);
  k_feats<<<512,256,0,stream>>>(hsf, hsb, chvec, fvb, tagW, tagb, feats);
  k_argmax<<<64,256,0,stream>>>(feats, out + 128 + 16384);
  k_viterbi<<<128,64,0,stream>>>(feats, amask, trans, out);
}